// Round 3
// baseline (493.151 us; speedup 1.0000x reference)
//
#include <hip/hip_runtime.h>
#include <math.h>

#define NB    64
#define NS    4096
#define NHQ   32
#define NHKV  8
#define ND    128
#define NG    4            // NHQ / NHKV
#define WAVES 8
#define NTHREADS (WAVES*64)
#define ROUNDS ((NS/WAVES)/4)   // 128 rounds of 4 keys per wave

typedef float f32x4 __attribute__((ext_vector_type(4)));

// exact fp32 -> e4m3fn (RNE, clip +-448) returned as fp32
__device__ __forceinline__ float quant_e4m3(float x) {
    float a = fabsf(x);
    a = fminf(a, 448.0f);
    unsigned ui = __float_as_uint(a);
    int e  = (int)(ui >> 23) - 127;
    int se = (e < -6 ? -6 : e) - 3;          // step exponent (denormal step = 2^-9)
    float stp = __uint_as_float((unsigned)(se + 127) << 23);
    float qv  = rintf(a / stp) * stp;        // a/stp exact (stp is pow2), rintf = RNE
    return copysignf(qv, x);
}

__device__ __forceinline__ float4 ntld(const float* p) {
    f32x4 r = __builtin_nontemporal_load((const f32x4*)p);
    return make_float4(r.x, r.y, r.z, r.w);
}

__global__ __launch_bounds__(NTHREADS, 4) void attn_decode_quant(
    const float* __restrict__ qin,
    const float* __restrict__ kc,
    const float* __restrict__ vc,
    const float* __restrict__ qscale,
    float* __restrict__ out)
{
    __shared__ double s_acc[WAVES][NG][ND];   // 32 KB
    __shared__ double s_l[WAVES][NG];
    __shared__ float  s_m[WAVES][NG];
    __shared__ double s_w[WAVES][NG];
    __shared__ double s_lt[NG];
    __shared__ float  p_lds[WAVES][16];       // per-wave p for 4 keys x 4 groups

    const int bh   = blockIdx.x;          // 0..511
    const int b    = bh >> 3;
    const int h    = bh & 7;
    const int tid  = threadIdx.x;
    const int wave = tid >> 6;
    const int lane = tid & 63;
    const int c    = lane >> 4;           // cluster = key-within-round (0..3)
    const int e    = lane & 15;           // elem slot within cluster
    const int half = lane >> 5;
    const int l32  = lane & 31;

    // replicate reference: 1.0 / np.sqrt(128).astype(np.float32), applied as f32 mul
    const float sm_scale = (float)(1.0 / (double)sqrtf(128.0f));

    // q fragments in score layout: q[b, h*4+g, 4e + 64j .. +4)
    float4 qf[NG][2];
    {
        const float* qb = qin + ((size_t)b * NHQ + (size_t)h * NG) * ND;
        #pragma unroll
        for (int g = 0; g < NG; ++g) {
            #pragma unroll
            for (int j = 0; j < 2; ++j)
                qf[g][j] = *(const float4*)(qb + g * ND + 4 * e + 64 * j);
        }
    }

    const size_t rs = (size_t)NHKV * ND;  // 1024 dwords between consecutive s
    const float* kb = kc + ((size_t)b * NS * NHKV + h) * ND;
    const float* vb = vc + ((size_t)b * NS * NHKV + h) * ND;

    const int wbase = wave * (NS / WAVES);        // 512 keys per wave

    const float* kp = kb + (size_t)(wbase + c) * rs + 4 * e;       // + 4*r*rs per round, +64 for frag j=1
    const float* vp = vb + (size_t)(wbase + half) * rs + 4 * l32;  // + (4*r + 2*t)*rs

    float  m[NG];
    double l[NG];
    double acc[NG][4];
    #pragma unroll
    for (int g = 0; g < NG; ++g) {
        m[g] = -INFINITY; l[g] = 0.0;
        #pragma unroll
        for (int j = 0; j < 4; ++j) acc[g][j] = 0.0;
    }

    // K pipeline: 1 round deep
    float4 kka = ntld(kp);
    float4 kkb = ntld(kp + 64);

    for (int r = 0; r < ROUNDS; ++r) {
        // issue this round's V loads (consumed at end of round)
        const float* vr = vp + (size_t)(4 * r) * rs;
        float4 va0 = ntld(vr);              // key 4r + half
        float4 va1 = ntld(vr + 2 * rs);     // key 4r + 2 + half

        // issue next round's K loads
        int rn = (r + 1 < ROUNDS) ? (r + 1) : r;
        const float* kn = kp + (size_t)(4 * rn) * rs;
        float4 knA = ntld(kn);
        float4 knB = ntld(kn + 64);

        // ---- score phase: 4 keys, cluster layout ----
        float s[NG];
        #pragma unroll
        for (int g = 0; g < NG; ++g) {
            float sd = qf[g][0].x * kka.x;
            sd = fmaf(qf[g][0].y, kka.y, sd);
            sd = fmaf(qf[g][0].z, kka.z, sd);
            sd = fmaf(qf[g][0].w, kka.w, sd);
            sd = fmaf(qf[g][1].x, kkb.x, sd);
            sd = fmaf(qf[g][1].y, kkb.y, sd);
            sd = fmaf(qf[g][1].z, kkb.z, sd);
            sd = fmaf(qf[g][1].w, kkb.w, sd);
            s[g] = sd;
        }
        #pragma unroll
        for (int g = 0; g < NG; ++g) {
            #pragma unroll
            for (int mask = 1; mask < 16; mask <<= 1)
                s[g] += __shfl_xor(s[g], mask);
            s[g] *= sm_scale;
        }

        // wave-uniform round max per group (over the 4 clusters)
        float p[NG];
        #pragma unroll
        for (int g = 0; g < NG; ++g) {
            float rm = s[g];
            rm = fmaxf(rm, __shfl_xor(rm, 16));
            rm = fmaxf(rm, __shfl_xor(rm, 32));
            if (rm > m[g]) {                       // wave-uniform, rare
                double corr = exp((double)(m[g] - rm));   // exp(-inf)=0 first time
                l[g] *= corr;
                acc[g][0] *= corr; acc[g][1] *= corr;
                acc[g][2] *= corr; acc[g][3] *= corr;
                m[g] = rm;
            }
            p[g] = expf(s[g] - m[g]);              // fp32 exp as in numpy softmax
            l[g] += (double)p[g];                  // per-cluster-lane fp64 partial
        }

        // publish p to per-wave LDS slot: dword c*4+g
        {
            float pw = (e == 0) ? p[0] : (e == 1) ? p[1] : (e == 2) ? p[2] : p[3];
            if (e < 4) p_lds[wave][c * 4 + e] = pw;
        }

        // ---- accumulate phase: 2 iters x 2 keys (halves), old layout ----
        float4 pA = *(const float4*)&p_lds[wave][half * 4];       // key 4r+half
        float4 pB = *(const float4*)&p_lds[wave][8 + half * 4];   // key 4r+2+half
        {
            double vx = (double)va0.x, vy = (double)va0.y;
            double vz = (double)va0.z, vw = (double)va0.w;
            double p0 = (double)pA.x, p1 = (double)pA.y;
            double p2 = (double)pA.z, p3 = (double)pA.w;
            acc[0][0] = fma(p0, vx, acc[0][0]); acc[0][1] = fma(p0, vy, acc[0][1]);
            acc[0][2] = fma(p0, vz, acc[0][2]); acc[0][3] = fma(p0, vw, acc[0][3]);
            acc[1][0] = fma(p1, vx, acc[1][0]); acc[1][1] = fma(p1, vy, acc[1][1]);
            acc[1][2] = fma(p1, vz, acc[1][2]); acc[1][3] = fma(p1, vw, acc[1][3]);
            acc[2][0] = fma(p2, vx, acc[2][0]); acc[2][1] = fma(p2, vy, acc[2][1]);
            acc[2][2] = fma(p2, vz, acc[2][2]); acc[2][3] = fma(p2, vw, acc[2][3]);
            acc[3][0] = fma(p3, vx, acc[3][0]); acc[3][1] = fma(p3, vy, acc[3][1]);
            acc[3][2] = fma(p3, vz, acc[3][2]); acc[3][3] = fma(p3, vw, acc[3][3]);
        }
        {
            double vx = (double)va1.x, vy = (double)va1.y;
            double vz = (double)va1.z, vw = (double)va1.w;
            double p0 = (double)pB.x, p1 = (double)pB.y;
            double p2 = (double)pB.z, p3 = (double)pB.w;
            acc[0][0] = fma(p0, vx, acc[0][0]); acc[0][1] = fma(p0, vy, acc[0][1]);
            acc[0][2] = fma(p0, vz, acc[0][2]); acc[0][3] = fma(p0, vw, acc[0][3]);
            acc[1][0] = fma(p1, vx, acc[1][0]); acc[1][1] = fma(p1, vy, acc[1][1]);
            acc[1][2] = fma(p1, vz, acc[1][2]); acc[1][3] = fma(p1, vw, acc[1][3]);
            acc[2][0] = fma(p2, vx, acc[2][0]); acc[2][1] = fma(p2, vy, acc[2][1]);
            acc[2][2] = fma(p2, vz, acc[2][2]); acc[2][3] = fma(p2, vw, acc[2][3]);
            acc[3][0] = fma(p3, vx, acc[3][0]); acc[3][1] = fma(p3, vy, acc[3][1]);
            acc[3][2] = fma(p3, vz, acc[3][2]); acc[3][3] = fma(p3, vw, acc[3][3]);
        }

        kka = knA; kkb = knB;
    }

    // merge l across the 4 clusters (each cluster's lanes hold identical l)
    #pragma unroll
    for (int g = 0; g < NG; ++g) {
        l[g] += __shfl_xor(l[g], 16);
        l[g] += __shfl_xor(l[g], 32);
    }
    // merge acc across halves (disjoint key sets, same m)
    #pragma unroll
    for (int g = 0; g < NG; ++g) {
        #pragma unroll
        for (int j = 0; j < 4; ++j)
            acc[g][j] += __shfl_xor(acc[g][j], 32);
    }

    if (half == 0) {
        #pragma unroll
        for (int g = 0; g < NG; ++g) {
            #pragma unroll
            for (int j = 0; j < 4; ++j)
                s_acc[wave][g][l32 * 4 + j] = acc[g][j];
        }
        if (l32 == 0) {
            #pragma unroll
            for (int g = 0; g < NG; ++g) { s_m[wave][g] = m[g]; s_l[wave][g] = l[g]; }
        }
    }
    __syncthreads();

    // per-g global max + weights + denominator
    if (tid < NG) {
        int g = tid;
        float M = -INFINITY;
        for (int pa = 0; pa < WAVES; ++pa) M = fmaxf(M, s_m[pa][g]);
        double ltot = 0.0;
        for (int pa = 0; pa < WAVES; ++pa) {
            double w = exp((double)(s_m[pa][g] - M));
            s_w[pa][g] = w;
            ltot += s_l[pa][g] * w;
        }
        s_lt[g] = ltot;
    }
    __syncthreads();

    // 512 outputs, 512 threads: (g,d)
    {
        const float qs = qscale[0];
        int g = tid >> 7;
        int d = tid & 127;
        double o = 0.0;
        for (int pa = 0; pa < WAVES; ++pa)
            o += s_acc[pa][g][d] * s_w[pa][g];
        o /= s_lt[g];
        float x = (float)o;
        x = x / qs;
        out[((size_t)b * NHQ + (size_t)(h * NG + g)) * ND + d] = quant_e4m3(x);
    }
}

extern "C" void kernel_launch(void* const* d_in, const int* in_sizes, int n_in,
                              void* d_out, int out_size, void* d_ws, size_t ws_size,
                              hipStream_t stream) {
    (void)in_sizes; (void)n_in; (void)d_ws; (void)ws_size; (void)out_size;
    const float* q  = (const float*)d_in[0];
    const float* k  = (const float*)d_in[1];
    const float* v  = (const float*)d_in[2];
    const float* qs = (const float*)d_in[3];
    float* o = (float*)d_out;
    hipLaunchKernelGGL(attn_decode_quant, dim3(NB * NHKV), dim3(NTHREADS), 0, stream,
                       q, k, v, qs, o);
}